// Round 1
// baseline (313.541 us; speedup 1.0000x reference)
//
#include <hip/hip_runtime.h>

#define NUM_USERS 100000
#define NUM_ITEMS 50000
#define N_NODES   150000
#define N_EDGES   2000000
#define DIM       128
#define DIM4      32          // DIM/4 (float4 per row)
#define CH8       16          // DIM/8 (half8 chunks per row)
#define BATCH     4096
#define B_SHIFT   9
#define BUCK_N    (1 << B_SHIFT)                         // 512 nodes/bucket
#define NBUCK     ((N_NODES + BUCK_N - 1) >> B_SHIFT)    // 293
#define CHUNK     8192
#define NCHUNK    ((N_EDGES + CHUNK - 1) / CHUNK)        // 245
#define CAP       12288       // max staged edges per bucket (48 KB LDS)
#define CAPB      16384       // fixed tmp region capacity per bucket
#define MARK_BLOCKS 512       // 2*BATCH / 16 elems per 256-thread block
#define CONV_BLOCKS ((N_NODES * CH8 + 255) / 256)        // 9375

typedef _Float16 half_t;
typedef __attribute__((ext_vector_type(8))) _Float16 half8;

// ---------- pass C: bin edges into fixed bucket regions, packed (src<<9)|(dst&511) ----------
// bcur holds RELATIVE cursors (zeroed by memset); region base = bucket*CAPB.

__global__ void bucket_scatter_kernel(const int* __restrict__ src,
                                      const int* __restrict__ dst,
                                      int* __restrict__ bcur,
                                      int* __restrict__ tmp) {
    __shared__ int lhist[NBUCK];
    __shared__ int lcur[NBUCK];
    int t = threadIdx.x;  // 512
    int base = blockIdx.x * CHUNK;
    for (int i = t; i < NBUCK; i += 512) lhist[i] = 0;
    __syncthreads();
    for (int i = 0; i < CHUNK / 512; ++i) {
        int e = base + i * 512 + t;
        if (e < N_EDGES) atomicAdd(&lhist[dst[e] >> B_SHIFT], 1);
    }
    __syncthreads();
    for (int i = t; i < NBUCK; i += 512) {
        int c = lhist[i];
        lcur[i] = c ? (i * CAPB + atomicAdd(&bcur[i], c)) : 0;
    }
    __syncthreads();
    for (int i = 0; i < CHUNK / 512; ++i) {
        int e = base + i * 512 + t;
        if (e < N_EDGES) {
            int d = dst[e];
            int buck = d >> B_SHIFT;
            int pos = atomicAdd(&lcur[buck], 1);
            if (pos < (buck + 1) * CAPB)  // overflow guard (statistically unreachable)
                tmp[pos] = (src[e] << B_SHIFT) | (d & (BUCK_N - 1));
        }
    }
}

// ---------- pass D: global prefix (recomputed per block) + local hist/scan/counting sort ----------
// Emits row_start / rinv / sdeg / csr_src. 512 threads.

__global__ void place_kernel(const int* __restrict__ bcur,
                             const int* __restrict__ tmp,
                             int* __restrict__ row_start,
                             float* __restrict__ rinv,
                             float* __restrict__ sdeg,
                             int* __restrict__ csr_src) {
    __shared__ int lhist[BUCK_N];
    __shared__ int lofs[BUCK_N];
    __shared__ int ssc[512];
    __shared__ int outbuf[CAP];
    int b = blockIdx.x;
    int t = threadIdx.x;  // 512

    // global exclusive prefix over clamped bucket counts (cheap: 293 values)
    int c = 0;
    if (t < NBUCK) {
        c = bcur[t];
        if (c > CAPB) c = CAPB;
    }
    ssc[t] = c;
    __syncthreads();
    for (int off = 1; off < 512; off <<= 1) {
        int v = (t >= off) ? ssc[t - off] : 0;
        __syncthreads();
        ssc[t] += v;
        __syncthreads();
    }
    int beg = (b == 0) ? 0 : ssc[b - 1];
    int end = ssc[b];
    int cnt = end - beg;
    int tbase = b * CAPB;
    int n0 = b << B_SHIFT;
    int n1 = n0 + BUCK_N; if (n1 > N_NODES) n1 = N_NODES;
    if (b == NBUCK - 1 && t == 0) row_start[N_NODES] = end;

    lhist[t] = 0;  // 512 threads cover BUCK_N exactly
    __syncthreads();
    for (int e = t; e < cnt; e += 512)
        atomicAdd(&lhist[tmp[tbase + e] & (BUCK_N - 1)], 1);
    __syncthreads();

    // 512-wide exclusive scan of per-row degrees (reuse ssc)
    int v = lhist[t];
    ssc[t] = v;
    __syncthreads();
    for (int off = 1; off < 512; off <<= 1) {
        int u = (t >= off) ? ssc[t - off] : 0;
        __syncthreads();
        ssc[t] += u;
        __syncthreads();
    }
    int excl = ssc[t] - v;
    lofs[t] = excl;
    int node = n0 + t;
    if (node < n1) {
        row_start[node] = beg + excl;
        float d = (float)(v > 1 ? v : 1);
        float rr = rsqrtf(d);
        rinv[node] = rr;
        sdeg[node] = d * rr;  // sqrt(d)
    }
    __syncthreads();

    // counting sort into LDS, then coalesced write-out
    if (cnt <= CAP) {
        for (int e = t; e < cnt; e += 512) {
            int p = tmp[tbase + e];
            int pos = atomicAdd(&lofs[p & (BUCK_N - 1)], 1);
            outbuf[pos] = p >> B_SHIFT;
        }
        __syncthreads();
        for (int i = t; i < cnt; i += 512) csr_src[beg + i] = outbuf[i];
    } else {
        for (int e = t; e < cnt; e += 512) {
            int p = tmp[tbase + e];
            int pos = atomicAdd(&lofs[p & (BUCK_N - 1)], 1);
            csr_src[beg + pos] = p >> B_SHIFT;
        }
    }
}

// ---------- fused: mark (batch nodes + neighbors) | fp16 pre-scaled table ----------

__global__ void mark_conv_kernel(const float4* __restrict__ ue4,
                                 const float4* __restrict__ ie4,
                                 const float* __restrict__ rinv,
                                 half8* __restrict__ e16,
                                 const int* __restrict__ users,
                                 const int* __restrict__ items,
                                 const int* __restrict__ row_start,
                                 const int* __restrict__ csr_src,
                                 int* __restrict__ mark) {
    int bid = blockIdx.x;
    if (bid < MARK_BLOCKS) {
        int g = threadIdx.x >> 4;
        int lane = threadIdx.x & 15;
        int b = bid * 16 + g;  // 0..2*BATCH-1
        int node = (b < BATCH) ? users[b] : (NUM_USERS + items[b - BATCH]);
        if (lane == 0) mark[node] = 1;
        int beg = row_start[node], end = row_start[node + 1];
        for (int e = beg + lane; e < end; e += 16) mark[csr_src[e]] = 1;
        return;
    }
    int i = (bid - MARK_BLOCKS) * 256 + threadIdx.x;  // chunk index
    const int total = N_NODES * CH8;
    if (i >= total) return;
    int n = i >> 4;
    int j = i & 15;
    const float4* row = (n < NUM_USERS) ? ue4 + (size_t)n * DIM4
                                        : ie4 + (size_t)(n - NUM_USERS) * DIM4;
    float r = rinv[n];
    float4 f0 = row[2 * j];
    float4 f1 = row[2 * j + 1];
    half8 h;
    h[0] = (half_t)(r * f0.x); h[1] = (half_t)(r * f0.y);
    h[2] = (half_t)(r * f0.z); h[3] = (half_t)(r * f0.w);
    h[4] = (half_t)(r * f1.x); h[5] = (half_t)(r * f1.y);
    h[6] = (half_t)(r * f1.z); h[7] = (half_t)(r * f1.w);
    e16[i] = h;
}

// ---------- wave-per-row SpMM (fp16 rows, fp32 accumulate) ----------
// One wave64 per dst row: quarter q = lane>>4 handles edge-slot q of each
// 4-edge step; chunk c = lane&15 owns 16 B of the 256 B row. Source indices
// for up to 64 edges are loaded once (coalesced, 4 B/lane) and distributed
// via __shfl. Loop trip count is wave-uniform -> no intra-wave divergence
// (the old 16-lane-group layout ran every wave at max(deg of 4 rows)).
// 16-edge blocks issue 4 independent 16 B gathers back-to-back for MLP.
// Invalid edge slots shfl src=0 (hot row 0, L1-resident) and mask the add.

template <int MASKED>
__global__ __launch_bounds__(256) void spmm_wave_kernel(
        const half8* __restrict__ in16,
        const int* __restrict__ row_start,
        const int* __restrict__ csr_src,
        const float* __restrict__ rinv,
        const int* __restrict__ mark,
        half8* __restrict__ out16) {
    int n = blockIdx.x * 4 + (threadIdx.x >> 6);  // row = global wave id
    if (n >= N_NODES) return;
    if (MASKED && !mark[n]) return;               // wave-uniform
    int lane = threadIdx.x & 63;
    int q = lane >> 4;
    int c = lane & 15;
    int beg = row_start[n], end = row_start[n + 1];
    float a[8];
#pragma unroll
    for (int j = 0; j < 8; ++j) a[j] = 0.f;

    for (int base = beg; base < end; base += 64) {   // deg>64 is essentially unreachable
        int eidx = base + lane;
        int myedge = (eidx < end) ? csr_src[eidx] : 0;
        int m = end - base; if (m > 64) m = 64;
        int nblk = (m + 15) >> 4;                    // 16-edge blocks, <=4
        for (int blk = 0; blk < nblk; ++blk) {
            int sl = 16 * blk + q;                   // <= 63 always
            int s0 = __shfl(myedge, sl,      64);
            int s1 = __shfl(myedge, sl + 4,  64);
            int s2 = __shfl(myedge, sl + 8,  64);
            int s3 = __shfl(myedge, sl + 12, 64);
            half8 h0 = in16[(s0 << 4) + c];
            half8 h1 = in16[(s1 << 4) + c];
            half8 h2 = in16[(s2 << 4) + c];
            half8 h3 = in16[(s3 << 4) + c];
            int e0 = base + sl;
            if (e0 < end) {
#pragma unroll
                for (int j = 0; j < 8; ++j) a[j] += (float)h0[j];
            }
            if (e0 + 4 < end) {
#pragma unroll
                for (int j = 0; j < 8; ++j) a[j] += (float)h1[j];
            }
            if (e0 + 8 < end) {
#pragma unroll
                for (int j = 0; j < 8; ++j) a[j] += (float)h2[j];
            }
            if (e0 + 12 < end) {
#pragma unroll
                for (int j = 0; j < 8; ++j) a[j] += (float)h3[j];
            }
        }
    }

    // reduce the 4 quarters (each holds a partial sum of its edge subset)
#pragma unroll
    for (int j = 0; j < 8; ++j) {
        a[j] += __shfl_xor(a[j], 16, 64);
        a[j] += __shfl_xor(a[j], 32, 64);
    }
    if (q == 0) {
        float f = rinv[n]; f *= f;
        half8 o;
#pragma unroll
        for (int j = 0; j < 8; ++j) o[j] = (half_t)(a[j] * f);
        out16[((size_t)n << 4) + c] = o;   // 16 lanes x 16 B = 256 B coalesced
    }
}

// ---------- fused epilogue: acc = emb0 + sdeg*(w1+w2) + rinv*sum_N w2; dot ----------
// 128 threads = 4 batch elems x (2 nodes x 16 lanes). Lane owns 8 channels.

__global__ void epilogue_kernel(const float4* __restrict__ ue4,
                                const float4* __restrict__ ie4,
                                const half8* __restrict__ w1,
                                const half8* __restrict__ w2,
                                const int* __restrict__ row_start,
                                const int* __restrict__ csr_src,
                                const float* __restrict__ rinv,
                                const float* __restrict__ sdeg,
                                const int* __restrict__ users,
                                const int* __restrict__ items,
                                float* __restrict__ out) {
    int t = threadIdx.x;
    int elem = blockIdx.x * 4 + (t >> 5);
    int half = (t >> 4) & 1;
    int lane = t & 15;
    int node = half ? (NUM_USERS + items[elem]) : users[elem];

    const float4* erow = (node < NUM_USERS) ? ue4 + (size_t)node * DIM4
                                            : ie4 + (size_t)(node - NUM_USERS) * DIM4;
    float4 f0 = erow[2 * lane];
    float4 f1 = erow[2 * lane + 1];
    float a[8] = {f0.x, f0.y, f0.z, f0.w, f1.x, f1.y, f1.z, f1.w};

    float sd = sdeg[node];
    half8 h1 = w1[(size_t)node * CH8 + lane];
    half8 h2 = w2[(size_t)node * CH8 + lane];
#pragma unroll
    for (int j = 0; j < 8; ++j) a[j] += sd * ((float)h1[j] + (float)h2[j]);

    int beg = row_start[node], end = row_start[node + 1];
    float a3[8];
#pragma unroll
    for (int j = 0; j < 8; ++j) a3[j] = 0.f;
    int e = beg;
    for (; e + 2 <= end; e += 2) {
        int s0 = csr_src[e], s1 = csr_src[e + 1];
        half8 g0 = w2[(size_t)s0 * CH8 + lane];
        half8 g1 = w2[(size_t)s1 * CH8 + lane];
#pragma unroll
        for (int j = 0; j < 8; ++j) a3[j] += (float)g0[j] + (float)g1[j];
    }
    if (e < end) {
        int s0 = csr_src[e];
        half8 g0 = w2[(size_t)s0 * CH8 + lane];
#pragma unroll
        for (int j = 0; j < 8; ++j) a3[j] += (float)g0[j];
    }
    float rv = rinv[node];
#pragma unroll
    for (int j = 0; j < 8; ++j) a[j] += rv * a3[j];

    int wl = t & 63;
    float p = 0.f;
#pragma unroll
    for (int j = 0; j < 8; ++j) p += a[j] * __shfl(a[j], wl ^ 16, 64);
    for (int off = 8; off > 0; off >>= 1) p += __shfl_down(p, off, 16);
    if (half == 0 && lane == 0) out[elem] = p * (1.0f / 16.0f);
}

extern "C" void kernel_launch(void* const* d_in, const int* in_sizes, int n_in,
                              void* d_out, int out_size, void* d_ws, size_t ws_size,
                              hipStream_t stream) {
    const float4* ue4 = (const float4*)d_in[0];
    const float4* ie4 = (const float4*)d_in[1];
    const int*   src   = (const int*)d_in[2];
    const int*   dst   = (const int*)d_in[3];
    const int*   users = (const int*)d_in[5];
    const int*   items = (const int*)d_in[6];
    float* out = (float*)d_out;

    const size_t h8elems = (size_t)N_NODES * CH8;
    char* ws = (char*)d_ws;
    half8* e16       = (half8*)ws;  ws += h8elems * sizeof(half8);
    half8* w1        = (half8*)ws;  ws += h8elems * sizeof(half8);
    half8* w2        = (half8*)ws;  ws += h8elems * sizeof(half8);
    int*   row_start = (int*)ws;    ws += (size_t)(N_NODES + 1) * sizeof(int);
    float* rinv      = (float*)ws;  ws += (size_t)N_NODES * sizeof(float);
    float* sdeg      = (float*)ws;  ws += (size_t)N_NODES * sizeof(float);
    int*   mark      = (int*)ws;    ws += (size_t)N_NODES * sizeof(int);
    int*   bcur      = (int*)ws;    ws += (size_t)NBUCK * sizeof(int);   // adjacent to mark
    ws = (char*)(((size_t)ws + 255) & ~(size_t)255);
    int*   tmp       = (int*)ws;    ws += (size_t)NBUCK * CAPB * sizeof(int);
    int*   csr_src   = (int*)ws;    ws += (size_t)N_EDGES * sizeof(int);

    // one memset covers mark + bcur (contiguous)
    hipMemsetAsync(mark, 0, (size_t)N_NODES * sizeof(int) + (size_t)NBUCK * sizeof(int), stream);

    // --- binned CSR build ---
    bucket_scatter_kernel<<<NCHUNK, 512, 0, stream>>>(src, dst, bcur, tmp);
    place_kernel<<<NBUCK, 512, 0, stream>>>(bcur, tmp, row_start, rinv, sdeg, csr_src);

    // --- fused mark + fp16 pre-scaled table ---
    mark_conv_kernel<<<MARK_BLOCKS + CONV_BLOCKS, 256, 0, stream>>>(
        ue4, ie4, rinv, e16, users, items, row_start, csr_src, mark);

    // --- layer 1 (all rows), wave-per-row ---
    spmm_wave_kernel<0><<<(N_NODES + 3) / 4, 256, 0, stream>>>(
        e16, row_start, csr_src, rinv, nullptr, w1);

    // --- layer 2 (marked rows only), wave-per-row ---
    spmm_wave_kernel<1><<<(N_NODES + 3) / 4, 256, 0, stream>>>(
        w1, row_start, csr_src, rinv, mark, w2);

    // --- fused epilogue: layers 0-3 at batch rows + dot ---
    epilogue_kernel<<<BATCH / 4, 128, 0, stream>>>(
        ue4, ie4, w1, w2, row_start, csr_src, rinv, sdeg, users, items, out);
}

// Round 3
// 300.708 us; speedup vs baseline: 1.0427x; 1.0427x over previous
//
#include <hip/hip_runtime.h>

#define NUM_USERS 100000
#define NUM_ITEMS 50000
#define N_NODES   150000
#define N_EDGES   2000000
#define DIM       128
#define DIM4      32          // DIM/4 (float4 per row)
#define CH8       16          // DIM/8 (half8 chunks per row)
#define BATCH     4096
#define B_SHIFT   9
#define BUCK_N    (1 << B_SHIFT)                         // 512 nodes/bucket
#define NBUCK     ((N_NODES + BUCK_N - 1) >> B_SHIFT)    // 293
#define CHUNK     8192
#define NCHUNK    ((N_EDGES + CHUNK - 1) / CHUNK)        // 245
#define CAP       12288       // max staged edges per bucket (48 KB LDS)
#define CAPB      16384       // fixed tmp region capacity per bucket
#define MARK_BLOCKS 512       // 2*BATCH / 16 elems per 256-thread block
#define CONV_BLOCKS (((N_NODES + 1) * CH8 + 255) / 256)  // covers zero row too

typedef _Float16 half_t;
typedef __attribute__((ext_vector_type(8))) _Float16 half8;
typedef __attribute__((ext_vector_type(4))) float f32x4;   // native vector for nontemporal builtin

// ---------- pass C: bin edges into fixed bucket regions, packed (src<<9)|(dst&511) ----------
// bcur holds RELATIVE cursors (zeroed by memset); region base = bucket*CAPB.

__global__ void bucket_scatter_kernel(const int* __restrict__ src,
                                      const int* __restrict__ dst,
                                      int* __restrict__ bcur,
                                      int* __restrict__ tmp) {
    __shared__ int lhist[NBUCK];
    __shared__ int lcur[NBUCK];
    int t = threadIdx.x;  // 512
    int base = blockIdx.x * CHUNK;
    for (int i = t; i < NBUCK; i += 512) lhist[i] = 0;
    __syncthreads();
    for (int i = 0; i < CHUNK / 512; ++i) {
        int e = base + i * 512 + t;
        if (e < N_EDGES) atomicAdd(&lhist[dst[e] >> B_SHIFT], 1);
    }
    __syncthreads();
    for (int i = t; i < NBUCK; i += 512) {
        int c = lhist[i];
        lcur[i] = c ? (i * CAPB + atomicAdd(&bcur[i], c)) : 0;
    }
    __syncthreads();
    for (int i = 0; i < CHUNK / 512; ++i) {
        int e = base + i * 512 + t;
        if (e < N_EDGES) {
            int d = dst[e];
            int buck = d >> B_SHIFT;
            int pos = atomicAdd(&lcur[buck], 1);
            if (pos < (buck + 1) * CAPB)  // overflow guard (statistically unreachable)
                tmp[pos] = (src[e] << B_SHIFT) | (d & (BUCK_N - 1));
        }
    }
}

// ---------- pass D: global prefix (recomputed per block) + local hist/scan/counting sort ----------
// Emits row_start / rinv / sdeg / csr_src. 512 threads.

__global__ void place_kernel(const int* __restrict__ bcur,
                             const int* __restrict__ tmp,
                             int* __restrict__ row_start,
                             float* __restrict__ rinv,
                             float* __restrict__ sdeg,
                             int* __restrict__ csr_src) {
    __shared__ int lhist[BUCK_N];
    __shared__ int lofs[BUCK_N];
    __shared__ int ssc[512];
    __shared__ int outbuf[CAP];
    int b = blockIdx.x;
    int t = threadIdx.x;  // 512

    // global exclusive prefix over clamped bucket counts (cheap: 293 values)
    int c = 0;
    if (t < NBUCK) {
        c = bcur[t];
        if (c > CAPB) c = CAPB;
    }
    ssc[t] = c;
    __syncthreads();
    for (int off = 1; off < 512; off <<= 1) {
        int v = (t >= off) ? ssc[t - off] : 0;
        __syncthreads();
        ssc[t] += v;
        __syncthreads();
    }
    int beg = (b == 0) ? 0 : ssc[b - 1];
    int end = ssc[b];
    int cnt = end - beg;
    int tbase = b * CAPB;
    int n0 = b << B_SHIFT;
    int n1 = n0 + BUCK_N; if (n1 > N_NODES) n1 = N_NODES;
    if (b == NBUCK - 1 && t == 0) row_start[N_NODES] = end;

    lhist[t] = 0;  // 512 threads cover BUCK_N exactly
    __syncthreads();
    for (int e = t; e < cnt; e += 512)
        atomicAdd(&lhist[tmp[tbase + e] & (BUCK_N - 1)], 1);
    __syncthreads();

    // 512-wide exclusive scan of per-row degrees (reuse ssc)
    int v = lhist[t];
    ssc[t] = v;
    __syncthreads();
    for (int off = 1; off < 512; off <<= 1) {
        int u = (t >= off) ? ssc[t - off] : 0;
        __syncthreads();
        ssc[t] += u;
        __syncthreads();
    }
    int excl = ssc[t] - v;
    lofs[t] = excl;
    int node = n0 + t;
    if (node < n1) {
        row_start[node] = beg + excl;
        float d = (float)(v > 1 ? v : 1);
        float rr = rsqrtf(d);
        rinv[node] = rr;
        sdeg[node] = d * rr;  // sqrt(d)
    }
    __syncthreads();

    // counting sort into LDS, then coalesced write-out
    if (cnt <= CAP) {
        for (int e = t; e < cnt; e += 512) {
            int p = tmp[tbase + e];
            int pos = atomicAdd(&lofs[p & (BUCK_N - 1)], 1);
            outbuf[pos] = p >> B_SHIFT;
        }
        __syncthreads();
        for (int i = t; i < cnt; i += 512) csr_src[beg + i] = outbuf[i];
    } else {
        for (int e = t; e < cnt; e += 512) {
            int p = tmp[tbase + e];
            int pos = atomicAdd(&lofs[p & (BUCK_N - 1)], 1);
            csr_src[beg + pos] = p >> B_SHIFT;
        }
    }
}

// ---------- fused: mark (batch nodes + neighbors) | fp16 pre-scaled table ----------
// Also zero-fills row N_NODES of e16 and w1 (the clamp target for invalid edge
// slots in the SpMM — makes inner-loop masking free).

__global__ void mark_conv_kernel(const f32x4* __restrict__ ue4,
                                 const f32x4* __restrict__ ie4,
                                 const float* __restrict__ rinv,
                                 half8* __restrict__ e16,
                                 half8* __restrict__ w1,
                                 const int* __restrict__ users,
                                 const int* __restrict__ items,
                                 const int* __restrict__ row_start,
                                 const int* __restrict__ csr_src,
                                 int* __restrict__ mark) {
    int bid = blockIdx.x;
    if (bid < MARK_BLOCKS) {
        int g = threadIdx.x >> 4;
        int lane = threadIdx.x & 15;
        int b = bid * 16 + g;  // 0..2*BATCH-1
        int node = (b < BATCH) ? users[b] : (NUM_USERS + items[b - BATCH]);
        if (lane == 0) mark[node] = 1;
        int beg = row_start[node], end = row_start[node + 1];
        for (int e = beg + lane; e < end; e += 16) mark[csr_src[e]] = 1;
        return;
    }
    int i = (bid - MARK_BLOCKS) * 256 + threadIdx.x;  // chunk index
    const int total = (N_NODES + 1) * CH8;
    if (i >= total) return;
    int n = i >> 4;
    if (n >= N_NODES) {  // zero row (clamp target)
        half8 z;
#pragma unroll
        for (int j = 0; j < 8; ++j) z[j] = (half_t)0.f;
        e16[i] = z;
        w1[i] = z;
        return;
    }
    int j = i & 15;
    const f32x4* row = (n < NUM_USERS) ? ue4 + (size_t)n * DIM4
                                       : ie4 + (size_t)(n - NUM_USERS) * DIM4;
    float r = rinv[n];
    // non-temporal: 76.8 MB fp32 read-once stream — don't evict e16/csr from L2
    f32x4 f0 = __builtin_nontemporal_load(&row[2 * j]);
    f32x4 f1 = __builtin_nontemporal_load(&row[2 * j + 1]);
    half8 h;
    h[0] = (half_t)(r * f0.x); h[1] = (half_t)(r * f0.y);
    h[2] = (half_t)(r * f0.z); h[3] = (half_t)(r * f0.w);
    h[4] = (half_t)(r * f1.x); h[5] = (half_t)(r * f1.y);
    h[6] = (half_t)(r * f1.z); h[7] = (half_t)(r * f1.w);
    e16[i] = h;
}

// ---------- SpMM v2: 16-lane group per row, packed-fp16 accumulate ----------
// Lane owns one 16 B chunk of the 256 B row. csr indices loaded coalesced
// (4 B/lane per 16-edge window) and broadcast via __shfl. Invalid slots clamp
// to zero row N_NODES (L1-hot, exact no-op on add) -> no mask VALU.
// 4 gathers in flight per group = 16 per wave. Inner-loop VALU per gather:
// 1 shfl + addr + 4 v_pk_add_f16.

template <int MASKED>
__global__ __launch_bounds__(256) void spmm_pk_kernel(
        const half8* __restrict__ tab,       // (N_NODES+1) rows, row N_NODES = 0
        const int* __restrict__ row_start,
        const int* __restrict__ csr_src,
        const float* __restrict__ rinv,
        const int* __restrict__ mark,
        half8* __restrict__ out16) {
    int t = threadIdx.x;
    int n = blockIdx.x * 16 + (t >> 4);
    if (n >= N_NODES) return;
    if (MASKED && !mark[n]) return;
    int lane = t & 15;
    int gbase = t & 48;  // group base lane within wave64
    int beg = row_start[n], end = row_start[n + 1];
    half8 acc;
#pragma unroll
    for (int j = 0; j < 8; ++j) acc[j] = (half_t)0.f;

    for (int base = beg; base < end; base += 16) {
        int eidx = base + lane;
        int myedge = (eidx < end) ? csr_src[eidx] : N_NODES;  // clamp -> zero row
        int m = end - base; if (m > 16) m = 16;
        int nblk = (m + 3) >> 2;
        for (int blk = 0; blk < nblk; ++blk) {
            int sb = gbase + blk * 4;
            int s0 = __shfl(myedge, sb,     64);
            int s1 = __shfl(myedge, sb + 1, 64);
            int s2 = __shfl(myedge, sb + 2, 64);
            int s3 = __shfl(myedge, sb + 3, 64);
            half8 h0 = tab[(s0 << 4) + lane];
            half8 h1 = tab[(s1 << 4) + lane];
            half8 h2 = tab[(s2 << 4) + lane];
            half8 h3 = tab[(s3 << 4) + lane];
            acc = acc + ((h0 + h1) + (h2 + h3));   // v_pk_add_f16, exact +0 for clamped
        }
    }

    float f = rinv[n]; f *= f;
    half_t hf = (half_t)f;
    half8 o = acc * hf;
    out16[((size_t)n << 4) + lane] = o;  // 16 lanes x 16 B = 256 B coalesced
}

// ---------- fused epilogue: acc = emb0 + sdeg*(w1+w2) + rinv*sum_N w2; dot ----------
// 128 threads = 4 batch elems x (2 nodes x 16 lanes). Lane owns 8 channels.

__global__ void epilogue_kernel(const f32x4* __restrict__ ue4,
                                const f32x4* __restrict__ ie4,
                                const half8* __restrict__ w1,
                                const half8* __restrict__ w2,
                                const int* __restrict__ row_start,
                                const int* __restrict__ csr_src,
                                const float* __restrict__ rinv,
                                const float* __restrict__ sdeg,
                                const int* __restrict__ users,
                                const int* __restrict__ items,
                                float* __restrict__ out) {
    int t = threadIdx.x;
    int elem = blockIdx.x * 4 + (t >> 5);
    int half = (t >> 4) & 1;
    int lane = t & 15;
    int node = half ? (NUM_USERS + items[elem]) : users[elem];

    const f32x4* erow = (node < NUM_USERS) ? ue4 + (size_t)node * DIM4
                                           : ie4 + (size_t)(node - NUM_USERS) * DIM4;
    f32x4 f0 = erow[2 * lane];
    f32x4 f1 = erow[2 * lane + 1];
    float a[8] = {f0.x, f0.y, f0.z, f0.w, f1.x, f1.y, f1.z, f1.w};

    float sd = sdeg[node];
    half8 h1 = w1[(size_t)node * CH8 + lane];
    half8 h2 = w2[(size_t)node * CH8 + lane];
#pragma unroll
    for (int j = 0; j < 8; ++j) a[j] += sd * ((float)h1[j] + (float)h2[j]);

    int beg = row_start[node], end = row_start[node + 1];
    float a3[8];
#pragma unroll
    for (int j = 0; j < 8; ++j) a3[j] = 0.f;
    int e = beg;
    for (; e + 2 <= end; e += 2) {
        int s0 = csr_src[e], s1 = csr_src[e + 1];
        half8 g0 = w2[(size_t)s0 * CH8 + lane];
        half8 g1 = w2[(size_t)s1 * CH8 + lane];
#pragma unroll
        for (int j = 0; j < 8; ++j) a3[j] += (float)g0[j] + (float)g1[j];
    }
    if (e < end) {
        int s0 = csr_src[e];
        half8 g0 = w2[(size_t)s0 * CH8 + lane];
#pragma unroll
        for (int j = 0; j < 8; ++j) a3[j] += (float)g0[j];
    }
    float rv = rinv[node];
#pragma unroll
    for (int j = 0; j < 8; ++j) a[j] += rv * a3[j];

    int wl = t & 63;
    float p = 0.f;
#pragma unroll
    for (int j = 0; j < 8; ++j) p += a[j] * __shfl(a[j], wl ^ 16, 64);
    for (int off = 8; off > 0; off >>= 1) p += __shfl_down(p, off, 16);
    if (half == 0 && lane == 0) out[elem] = p * (1.0f / 16.0f);
}

extern "C" void kernel_launch(void* const* d_in, const int* in_sizes, int n_in,
                              void* d_out, int out_size, void* d_ws, size_t ws_size,
                              hipStream_t stream) {
    const f32x4* ue4 = (const f32x4*)d_in[0];
    const f32x4* ie4 = (const f32x4*)d_in[1];
    const int*   src   = (const int*)d_in[2];
    const int*   dst   = (const int*)d_in[3];
    const int*   users = (const int*)d_in[5];
    const int*   items = (const int*)d_in[6];
    float* out = (float*)d_out;

    const size_t h8rows = (size_t)(N_NODES + 1) * CH8;   // +1 zero row for e16/w1
    char* ws = (char*)d_ws;
    half8* e16       = (half8*)ws;  ws += h8rows * sizeof(half8);
    half8* w1        = (half8*)ws;  ws += h8rows * sizeof(half8);
    half8* w2        = (half8*)ws;  ws += (size_t)N_NODES * CH8 * sizeof(half8);
    int*   row_start = (int*)ws;    ws += (size_t)(N_NODES + 1) * sizeof(int);
    float* rinv      = (float*)ws;  ws += (size_t)N_NODES * sizeof(float);
    float* sdeg      = (float*)ws;  ws += (size_t)N_NODES * sizeof(float);
    int*   mark      = (int*)ws;    ws += (size_t)N_NODES * sizeof(int);
    int*   bcur      = (int*)ws;    ws += (size_t)NBUCK * sizeof(int);   // adjacent to mark
    ws = (char*)(((size_t)ws + 255) & ~(size_t)255);
    int*   tmp       = (int*)ws;    ws += (size_t)NBUCK * CAPB * sizeof(int);
    int*   csr_src   = (int*)ws;    ws += (size_t)N_EDGES * sizeof(int);

    // one memset covers mark + bcur (contiguous)
    hipMemsetAsync(mark, 0, (size_t)N_NODES * sizeof(int) + (size_t)NBUCK * sizeof(int), stream);

    // --- binned CSR build ---
    bucket_scatter_kernel<<<NCHUNK, 512, 0, stream>>>(src, dst, bcur, tmp);
    place_kernel<<<NBUCK, 512, 0, stream>>>(bcur, tmp, row_start, rinv, sdeg, csr_src);

    // --- fused mark + fp16 pre-scaled table (+ zero row init) ---
    mark_conv_kernel<<<MARK_BLOCKS + CONV_BLOCKS, 256, 0, stream>>>(
        ue4, ie4, rinv, e16, w1, users, items, row_start, csr_src, mark);

    // --- layer 1 (all rows) ---
    spmm_pk_kernel<0><<<(N_NODES + 15) / 16, 256, 0, stream>>>(
        e16, row_start, csr_src, rinv, nullptr, w1);

    // --- layer 2 (marked rows only) ---
    spmm_pk_kernel<1><<<(N_NODES + 15) / 16, 256, 0, stream>>>(
        w1, row_start, csr_src, rinv, mark, w2);

    // --- fused epilogue: layers 0-3 at batch rows + dot ---
    epilogue_kernel<<<BATCH / 4, 128, 0, stream>>>(
        ue4, ie4, w1, w2, row_start, csr_src, rinv, sdeg, users, items, out);
}

// Round 4
// 300.410 us; speedup vs baseline: 1.0437x; 1.0010x over previous
//
#include <hip/hip_runtime.h>

#define NUM_USERS 100000
#define NUM_ITEMS 50000
#define N_NODES   150000
#define N_EDGES   2000000
#define DIM       128
#define DIM4      32          // DIM/4 (float4 per row)
#define CH8       16          // DIM/8 (half8 chunks per row)
#define BATCH     4096
#define B_SHIFT   9
#define BUCK_N    (1 << B_SHIFT)                         // 512 nodes/bucket
#define NBUCK     ((N_NODES + BUCK_N - 1) >> B_SHIFT)    // 293
#define CHUNK     8192
#define NCHUNK    ((N_EDGES + CHUNK - 1) / CHUNK)        // 245
#define CAP       12288       // max staged edges per bucket (48 KB LDS)
#define CAPB      16384       // fixed tmp region capacity per bucket
#define MARK_BLOCKS 512       // 2*BATCH / 16 elems per 256-thread block
#define CONV_BLOCKS (((N_NODES + 1) * CH8 + 255) / 256)  // covers zero row too

typedef _Float16 half_t;
typedef __attribute__((ext_vector_type(8))) _Float16 half8;
typedef __attribute__((ext_vector_type(4))) float f32x4;   // native vector for nontemporal builtin

// ---------- pass C: bin edges into fixed bucket regions, packed (src<<9)|(dst&511) ----------
// bcur holds RELATIVE cursors (zeroed by memset); region base = bucket*CAPB.

__global__ void bucket_scatter_kernel(const int* __restrict__ src,
                                      const int* __restrict__ dst,
                                      int* __restrict__ bcur,
                                      int* __restrict__ tmp) {
    __shared__ int lhist[NBUCK];
    __shared__ int lcur[NBUCK];
    int t = threadIdx.x;  // 512
    int base = blockIdx.x * CHUNK;
    for (int i = t; i < NBUCK; i += 512) lhist[i] = 0;
    __syncthreads();
    for (int i = 0; i < CHUNK / 512; ++i) {
        int e = base + i * 512 + t;
        if (e < N_EDGES) atomicAdd(&lhist[dst[e] >> B_SHIFT], 1);
    }
    __syncthreads();
    for (int i = t; i < NBUCK; i += 512) {
        int c = lhist[i];
        lcur[i] = c ? (i * CAPB + atomicAdd(&bcur[i], c)) : 0;
    }
    __syncthreads();
    for (int i = 0; i < CHUNK / 512; ++i) {
        int e = base + i * 512 + t;
        if (e < N_EDGES) {
            int d = dst[e];
            int buck = d >> B_SHIFT;
            int pos = atomicAdd(&lcur[buck], 1);
            if (pos < (buck + 1) * CAPB)  // overflow guard (statistically unreachable)
                tmp[pos] = (src[e] << B_SHIFT) | (d & (BUCK_N - 1));
        }
    }
}

// ---------- pass D: global prefix (recomputed per block) + local hist/scan/counting sort ----------
// Emits row_start / rinv / sdeg / csr_src. 512 threads.

__global__ void place_kernel(const int* __restrict__ bcur,
                             const int* __restrict__ tmp,
                             int* __restrict__ row_start,
                             float* __restrict__ rinv,
                             float* __restrict__ sdeg,
                             int* __restrict__ csr_src) {
    __shared__ int lhist[BUCK_N];
    __shared__ int lofs[BUCK_N];
    __shared__ int ssc[512];
    __shared__ int outbuf[CAP];
    int b = blockIdx.x;
    int t = threadIdx.x;  // 512

    // global exclusive prefix over clamped bucket counts (cheap: 293 values)
    int c = 0;
    if (t < NBUCK) {
        c = bcur[t];
        if (c > CAPB) c = CAPB;
    }
    ssc[t] = c;
    __syncthreads();
    for (int off = 1; off < 512; off <<= 1) {
        int v = (t >= off) ? ssc[t - off] : 0;
        __syncthreads();
        ssc[t] += v;
        __syncthreads();
    }
    int beg = (b == 0) ? 0 : ssc[b - 1];
    int end = ssc[b];
    int cnt = end - beg;
    int tbase = b * CAPB;
    int n0 = b << B_SHIFT;
    int n1 = n0 + BUCK_N; if (n1 > N_NODES) n1 = N_NODES;
    if (b == NBUCK - 1 && t == 0) row_start[N_NODES] = end;

    lhist[t] = 0;  // 512 threads cover BUCK_N exactly
    __syncthreads();
    for (int e = t; e < cnt; e += 512)
        atomicAdd(&lhist[tmp[tbase + e] & (BUCK_N - 1)], 1);
    __syncthreads();

    // 512-wide exclusive scan of per-row degrees (reuse ssc)
    int v = lhist[t];
    ssc[t] = v;
    __syncthreads();
    for (int off = 1; off < 512; off <<= 1) {
        int u = (t >= off) ? ssc[t - off] : 0;
        __syncthreads();
        ssc[t] += u;
        __syncthreads();
    }
    int excl = ssc[t] - v;
    lofs[t] = excl;
    int node = n0 + t;
    if (node < n1) {
        row_start[node] = beg + excl;
        float d = (float)(v > 1 ? v : 1);
        float rr = rsqrtf(d);
        rinv[node] = rr;
        sdeg[node] = d * rr;  // sqrt(d)
    }
    __syncthreads();

    // counting sort into LDS, then coalesced write-out
    if (cnt <= CAP) {
        for (int e = t; e < cnt; e += 512) {
            int p = tmp[tbase + e];
            int pos = atomicAdd(&lofs[p & (BUCK_N - 1)], 1);
            outbuf[pos] = p >> B_SHIFT;
        }
        __syncthreads();
        for (int i = t; i < cnt; i += 512) csr_src[beg + i] = outbuf[i];
    } else {
        for (int e = t; e < cnt; e += 512) {
            int p = tmp[tbase + e];
            int pos = atomicAdd(&lofs[p & (BUCK_N - 1)], 1);
            csr_src[beg + pos] = p >> B_SHIFT;
        }
    }
}

// ---------- fused: mark (batch nodes + neighbors) | fp16 pre-scaled table ----------
// Also zero-fills row N_NODES of e16 and w1 (the clamp target for invalid edge
// slots in the SpMM — makes inner-loop masking free).

__global__ void mark_conv_kernel(const f32x4* __restrict__ ue4,
                                 const f32x4* __restrict__ ie4,
                                 const float* __restrict__ rinv,
                                 half8* __restrict__ e16,
                                 half8* __restrict__ w1,
                                 const int* __restrict__ users,
                                 const int* __restrict__ items,
                                 const int* __restrict__ row_start,
                                 const int* __restrict__ csr_src,
                                 int* __restrict__ mark) {
    int bid = blockIdx.x;
    if (bid < MARK_BLOCKS) {
        int g = threadIdx.x >> 4;
        int lane = threadIdx.x & 15;
        int b = bid * 16 + g;  // 0..2*BATCH-1
        int node = (b < BATCH) ? users[b] : (NUM_USERS + items[b - BATCH]);
        if (lane == 0) mark[node] = 1;
        int beg = row_start[node], end = row_start[node + 1];
        for (int e = beg + lane; e < end; e += 16) mark[csr_src[e]] = 1;
        return;
    }
    int i = (bid - MARK_BLOCKS) * 256 + threadIdx.x;  // chunk index
    const int total = (N_NODES + 1) * CH8;
    if (i >= total) return;
    int n = i >> 4;
    if (n >= N_NODES) {  // zero row (clamp target)
        half8 z;
#pragma unroll
        for (int j = 0; j < 8; ++j) z[j] = (half_t)0.f;
        e16[i] = z;
        w1[i] = z;
        return;
    }
    int j = i & 15;
    const f32x4* row = (n < NUM_USERS) ? ue4 + (size_t)n * DIM4
                                       : ie4 + (size_t)(n - NUM_USERS) * DIM4;
    float r = rinv[n];
    // non-temporal: 76.8 MB fp32 read-once stream — don't evict e16/csr from L2
    f32x4 f0 = __builtin_nontemporal_load(&row[2 * j]);
    f32x4 f1 = __builtin_nontemporal_load(&row[2 * j + 1]);
    half8 h;
    h[0] = (half_t)(r * f0.x); h[1] = (half_t)(r * f0.y);
    h[2] = (half_t)(r * f0.z); h[3] = (half_t)(r * f0.w);
    h[4] = (half_t)(r * f1.x); h[5] = (half_t)(r * f1.y);
    h[6] = (half_t)(r * f1.z); h[7] = (half_t)(r * f1.w);
    e16[i] = h;
}

// ---------- SpMM v3: 16-lane group per row, FULL-WINDOW load issue ----------
// Lane owns one 16 B chunk of the 256 B row. Per 16-edge window: 1 coalesced
// csr load, 16 shfl broadcasts, then ALL 16 row-gathers issued back-to-back
// (64 loads in flight per wave vs 16 before — attacks the latency bound).
// Pairwise tree accumulate written in load order so the compiler can drain
// vmcnt incrementally. Invalid slots clamp to zero row N_NODES (L1-hot,
// exact +0) -> no masking VALU, no divergence.

template <int MASKED>
__global__ __launch_bounds__(256) void spmm_pk_kernel(
        const half8* __restrict__ tab,       // (N_NODES+1) rows, row N_NODES = 0
        const int* __restrict__ row_start,
        const int* __restrict__ csr_src,
        const float* __restrict__ rinv,
        const int* __restrict__ mark,
        half8* __restrict__ out16) {
    int t = threadIdx.x;
    int n = blockIdx.x * 16 + (t >> 4);
    if (n >= N_NODES) return;
    if (MASKED && !mark[n]) return;
    int lane = t & 15;
    int gbase = t & 48;  // group base lane within wave64
    int beg = row_start[n], end = row_start[n + 1];
    const half8* tabl = tab + lane;   // lane-offset base; index by (s<<4)
    half8 acc;
#pragma unroll
    for (int j = 0; j < 8; ++j) acc[j] = (half_t)0.f;

    for (int base = beg; base < end; base += 16) {
        int eidx = base + lane;
        int myedge = (eidx < end) ? csr_src[eidx] : N_NODES;  // clamp -> zero row
        int s[16];
#pragma unroll
        for (int k = 0; k < 16; ++k) s[k] = __shfl(myedge, gbase + k, 64);
        half8 h[16];
#pragma unroll
        for (int k = 0; k < 16; ++k) h[k] = tabl[s[k] << 4];
        // pairwise tree in load order (compiler drains vmcnt incrementally)
        half8 p0 = h[0] + h[1];
        half8 p1 = h[2] + h[3];
        half8 p2 = h[4] + h[5];
        half8 p3 = h[6] + h[7];
        half8 p4 = h[8] + h[9];
        half8 p5 = h[10] + h[11];
        half8 p6 = h[12] + h[13];
        half8 p7 = h[14] + h[15];
        half8 q0 = p0 + p1;
        half8 q1 = p2 + p3;
        half8 q2 = p4 + p5;
        half8 q3 = p6 + p7;
        acc = acc + ((q0 + q1) + (q2 + q3));
    }

    float f = rinv[n]; f *= f;
    half_t hf = (half_t)f;
    half8 o = acc * hf;
    out16[((size_t)n << 4) + lane] = o;  // 16 lanes x 16 B = 256 B coalesced
}

// ---------- fused epilogue: acc = emb0 + sdeg*(w1+w2) + rinv*sum_N w2; dot ----------
// 128 threads = 4 batch elems x (2 nodes x 16 lanes). Lane owns 8 channels.

__global__ void epilogue_kernel(const f32x4* __restrict__ ue4,
                                const f32x4* __restrict__ ie4,
                                const half8* __restrict__ w1,
                                const half8* __restrict__ w2,
                                const int* __restrict__ row_start,
                                const int* __restrict__ csr_src,
                                const float* __restrict__ rinv,
                                const float* __restrict__ sdeg,
                                const int* __restrict__ users,
                                const int* __restrict__ items,
                                float* __restrict__ out) {
    int t = threadIdx.x;
    int elem = blockIdx.x * 4 + (t >> 5);
    int half = (t >> 4) & 1;
    int lane = t & 15;
    int node = half ? (NUM_USERS + items[elem]) : users[elem];

    const f32x4* erow = (node < NUM_USERS) ? ue4 + (size_t)node * DIM4
                                           : ie4 + (size_t)(node - NUM_USERS) * DIM4;
    f32x4 f0 = erow[2 * lane];
    f32x4 f1 = erow[2 * lane + 1];
    float a[8] = {f0.x, f0.y, f0.z, f0.w, f1.x, f1.y, f1.z, f1.w};

    float sd = sdeg[node];
    half8 h1 = w1[(size_t)node * CH8 + lane];
    half8 h2 = w2[(size_t)node * CH8 + lane];
#pragma unroll
    for (int j = 0; j < 8; ++j) a[j] += sd * ((float)h1[j] + (float)h2[j]);

    int beg = row_start[node], end = row_start[node + 1];
    float a3[8];
#pragma unroll
    for (int j = 0; j < 8; ++j) a3[j] = 0.f;
    int e = beg;
    for (; e + 2 <= end; e += 2) {
        int s0 = csr_src[e], s1 = csr_src[e + 1];
        half8 g0 = w2[(size_t)s0 * CH8 + lane];
        half8 g1 = w2[(size_t)s1 * CH8 + lane];
#pragma unroll
        for (int j = 0; j < 8; ++j) a3[j] += (float)g0[j] + (float)g1[j];
    }
    if (e < end) {
        int s0 = csr_src[e];
        half8 g0 = w2[(size_t)s0 * CH8 + lane];
#pragma unroll
        for (int j = 0; j < 8; ++j) a3[j] += (float)g0[j];
    }
    float rv = rinv[node];
#pragma unroll
    for (int j = 0; j < 8; ++j) a[j] += rv * a3[j];

    int wl = t & 63;
    float p = 0.f;
#pragma unroll
    for (int j = 0; j < 8; ++j) p += a[j] * __shfl(a[j], wl ^ 16, 64);
    for (int off = 8; off > 0; off >>= 1) p += __shfl_down(p, off, 16);
    if (half == 0 && lane == 0) out[elem] = p * (1.0f / 16.0f);
}

extern "C" void kernel_launch(void* const* d_in, const int* in_sizes, int n_in,
                              void* d_out, int out_size, void* d_ws, size_t ws_size,
                              hipStream_t stream) {
    const f32x4* ue4 = (const f32x4*)d_in[0];
    const f32x4* ie4 = (const f32x4*)d_in[1];
    const int*   src   = (const int*)d_in[2];
    const int*   dst   = (const int*)d_in[3];
    const int*   users = (const int*)d_in[5];
    const int*   items = (const int*)d_in[6];
    float* out = (float*)d_out;

    const size_t h8rows = (size_t)(N_NODES + 1) * CH8;   // +1 zero row for e16/w1
    char* ws = (char*)d_ws;
    half8* e16       = (half8*)ws;  ws += h8rows * sizeof(half8);
    half8* w1        = (half8*)ws;  ws += h8rows * sizeof(half8);
    half8* w2        = (half8*)ws;  ws += (size_t)N_NODES * CH8 * sizeof(half8);
    int*   row_start = (int*)ws;    ws += (size_t)(N_NODES + 1) * sizeof(int);
    float* rinv      = (float*)ws;  ws += (size_t)N_NODES * sizeof(float);
    float* sdeg      = (float*)ws;  ws += (size_t)N_NODES * sizeof(float);
    int*   mark      = (int*)ws;    ws += (size_t)N_NODES * sizeof(int);
    int*   bcur      = (int*)ws;    ws += (size_t)NBUCK * sizeof(int);   // adjacent to mark
    ws = (char*)(((size_t)ws + 255) & ~(size_t)255);
    int*   tmp       = (int*)ws;    ws += (size_t)NBUCK * CAPB * sizeof(int);
    int*   csr_src   = (int*)ws;    ws += (size_t)N_EDGES * sizeof(int);

    // one memset covers mark + bcur (contiguous)
    hipMemsetAsync(mark, 0, (size_t)N_NODES * sizeof(int) + (size_t)NBUCK * sizeof(int), stream);

    // --- binned CSR build ---
    bucket_scatter_kernel<<<NCHUNK, 512, 0, stream>>>(src, dst, bcur, tmp);
    place_kernel<<<NBUCK, 512, 0, stream>>>(bcur, tmp, row_start, rinv, sdeg, csr_src);

    // --- fused mark + fp16 pre-scaled table (+ zero row init) ---
    mark_conv_kernel<<<MARK_BLOCKS + CONV_BLOCKS, 256, 0, stream>>>(
        ue4, ie4, rinv, e16, w1, users, items, row_start, csr_src, mark);

    // --- layer 1 (all rows) ---
    spmm_pk_kernel<0><<<(N_NODES + 15) / 16, 256, 0, stream>>>(
        e16, row_start, csr_src, rinv, nullptr, w1);

    // --- layer 2 (marked rows only) ---
    spmm_pk_kernel<1><<<(N_NODES + 15) / 16, 256, 0, stream>>>(
        w1, row_start, csr_src, rinv, mark, w2);

    // --- fused epilogue: layers 0-3 at batch rows + dot ---
    epilogue_kernel<<<BATCH / 4, 128, 0, stream>>>(
        ue4, ie4, w1, w2, row_start, csr_src, rinv, sdeg, users, items, out);
}

// Round 5
// 266.506 us; speedup vs baseline: 1.1765x; 1.1272x over previous
//
#include <hip/hip_runtime.h>

#define NUM_USERS 100000
#define NUM_ITEMS 50000
#define N_NODES   150000
#define N_EDGES   2000000
#define DIM       128
#define DIM4      32          // DIM/4 (float4 per row)
#define BATCH     4096
#define B_SHIFT   9
#define BUCK_N    (1 << B_SHIFT)                         // 512 nodes/bucket
#define NBUCK     ((N_NODES + BUCK_N - 1) >> B_SHIFT)    // 293
#define CHUNK     8192
#define NCHUNK    ((N_EDGES + CHUNK - 1) / CHUNK)        // 245
#define CAP       12288       // max staged edges per bucket (48 KB LDS)
#define CAPB      16384       // fixed tmp region capacity per bucket
#define MARK_BLOCKS 512       // 2*BATCH / 16 elems per 256-thread block
#define CONV_BLOCKS (((N_NODES + 1) * 8 + 255) / 256)    // fp8 conv, 16ch/thread

// fp8 table gains (powers of 2, exact): keep values out of e4m3 subnormals.
// e16 stores x*rinv*G0; w1 stores w1_true*G1; w2 stores w2_true*G2.
// G1/G0 = G2/G1 = 4  ->  both spmm layers scale acc by 4*rinv^2.
#define G0 16.0f
#define INV_G1 (1.0f / 64.0f)
#define INV_G2 (1.0f / 256.0f)

typedef __attribute__((ext_vector_type(4))) float f32x4;
typedef __attribute__((ext_vector_type(2))) float f32x2;

// hw fp8 (OCP e4m3 on gfx950) <-> f32 pair converts
__device__ inline f32x2 f8x2_lo(unsigned w) { return __builtin_amdgcn_cvt_pk_f32_fp8(w, 0); }
__device__ inline f32x2 f8x2_hi(unsigned w) { return __builtin_amdgcn_cvt_pk_f32_fp8(w, 1); }
__device__ inline unsigned enc_lo(float a, float b, unsigned old) {
    return __builtin_amdgcn_cvt_pk_fp8_f32(a, b, old, 0);
}
__device__ inline unsigned enc_hi(float a, float b, unsigned old) {
    return __builtin_amdgcn_cvt_pk_fp8_f32(a, b, old, 1);
}

// ---------- pass C: bin edges into fixed bucket regions, packed (src<<9)|(dst&511) ----------

__global__ void bucket_scatter_kernel(const int* __restrict__ src,
                                      const int* __restrict__ dst,
                                      int* __restrict__ bcur,
                                      int* __restrict__ tmp) {
    __shared__ int lhist[NBUCK];
    __shared__ int lcur[NBUCK];
    int t = threadIdx.x;  // 512
    int base = blockIdx.x * CHUNK;
    for (int i = t; i < NBUCK; i += 512) lhist[i] = 0;
    __syncthreads();
    for (int i = 0; i < CHUNK / 512; ++i) {
        int e = base + i * 512 + t;
        if (e < N_EDGES) atomicAdd(&lhist[dst[e] >> B_SHIFT], 1);
    }
    __syncthreads();
    for (int i = t; i < NBUCK; i += 512) {
        int c = lhist[i];
        lcur[i] = c ? (i * CAPB + atomicAdd(&bcur[i], c)) : 0;
    }
    __syncthreads();
    for (int i = 0; i < CHUNK / 512; ++i) {
        int e = base + i * 512 + t;
        if (e < N_EDGES) {
            int d = dst[e];
            int buck = d >> B_SHIFT;
            int pos = atomicAdd(&lcur[buck], 1);
            if (pos < (buck + 1) * CAPB)  // overflow guard (statistically unreachable)
                tmp[pos] = (src[e] << B_SHIFT) | (d & (BUCK_N - 1));
        }
    }
}

// ---------- pass D: global prefix + local hist/scan/counting sort ----------

__global__ void place_kernel(const int* __restrict__ bcur,
                             const int* __restrict__ tmp,
                             int* __restrict__ row_start,
                             float* __restrict__ rinv,
                             float* __restrict__ sdeg,
                             int* __restrict__ csr_src) {
    __shared__ int lhist[BUCK_N];
    __shared__ int lofs[BUCK_N];
    __shared__ int ssc[512];
    __shared__ int outbuf[CAP];
    int b = blockIdx.x;
    int t = threadIdx.x;  // 512

    int c = 0;
    if (t < NBUCK) {
        c = bcur[t];
        if (c > CAPB) c = CAPB;
    }
    ssc[t] = c;
    __syncthreads();
    for (int off = 1; off < 512; off <<= 1) {
        int v = (t >= off) ? ssc[t - off] : 0;
        __syncthreads();
        ssc[t] += v;
        __syncthreads();
    }
    int beg = (b == 0) ? 0 : ssc[b - 1];
    int end = ssc[b];
    int cnt = end - beg;
    int tbase = b * CAPB;
    int n0 = b << B_SHIFT;
    int n1 = n0 + BUCK_N; if (n1 > N_NODES) n1 = N_NODES;
    if (b == NBUCK - 1 && t == 0) row_start[N_NODES] = end;

    lhist[t] = 0;
    __syncthreads();
    for (int e = t; e < cnt; e += 512)
        atomicAdd(&lhist[tmp[tbase + e] & (BUCK_N - 1)], 1);
    __syncthreads();

    int v = lhist[t];
    ssc[t] = v;
    __syncthreads();
    for (int off = 1; off < 512; off <<= 1) {
        int u = (t >= off) ? ssc[t - off] : 0;
        __syncthreads();
        ssc[t] += u;
        __syncthreads();
    }
    int excl = ssc[t] - v;
    lofs[t] = excl;
    int node = n0 + t;
    if (node < n1) {
        row_start[node] = beg + excl;
        float d = (float)(v > 1 ? v : 1);
        float rr = rsqrtf(d);
        rinv[node] = rr;
        sdeg[node] = d * rr;  // sqrt(d)
    }
    __syncthreads();

    if (cnt <= CAP) {
        for (int e = t; e < cnt; e += 512) {
            int p = tmp[tbase + e];
            int pos = atomicAdd(&lofs[p & (BUCK_N - 1)], 1);
            outbuf[pos] = p >> B_SHIFT;
        }
        __syncthreads();
        for (int i = t; i < cnt; i += 512) csr_src[beg + i] = outbuf[i];
    } else {
        for (int e = t; e < cnt; e += 512) {
            int p = tmp[tbase + e];
            int pos = atomicAdd(&lofs[p & (BUCK_N - 1)], 1);
            csr_src[beg + pos] = p >> B_SHIFT;
        }
    }
}

// ---------- fused: mark (batch nodes + neighbors) | fp8 pre-scaled table ----------
// Thread converts 16 channels (4 float4 -> uint4 of fp8). Also zero-fills the
// clamp row N_NODES of e16 and w1.

__global__ void mark_conv_kernel(const f32x4* __restrict__ ue4,
                                 const f32x4* __restrict__ ie4,
                                 const float* __restrict__ rinv,
                                 uint4* __restrict__ e16f8,
                                 uint4* __restrict__ w1f8,
                                 const int* __restrict__ users,
                                 const int* __restrict__ items,
                                 const int* __restrict__ row_start,
                                 const int* __restrict__ csr_src,
                                 int* __restrict__ mark) {
    int bid = blockIdx.x;
    if (bid < MARK_BLOCKS) {
        int g = threadIdx.x >> 4;
        int lane = threadIdx.x & 15;
        int b = bid * 16 + g;  // 0..2*BATCH-1
        int node = (b < BATCH) ? users[b] : (NUM_USERS + items[b - BATCH]);
        if (lane == 0) mark[node] = 1;
        int beg = row_start[node], end = row_start[node + 1];
        for (int e = beg + lane; e < end; e += 16) mark[csr_src[e]] = 1;
        return;
    }
    int i = (bid - MARK_BLOCKS) * 256 + threadIdx.x;  // (node, 16ch-chunk j)
    const int total = (N_NODES + 1) * 8;
    if (i >= total) return;
    int n = i >> 3;
    if (n >= N_NODES) {  // zero row (clamp target); i == N_NODES*8 + j
        uint4 z = make_uint4(0u, 0u, 0u, 0u);
        e16f8[i] = z;
        w1f8[i] = z;
        return;
    }
    int j = i & 7;
    const f32x4* row = (n < NUM_USERS) ? ue4 + (size_t)n * DIM4
                                       : ie4 + (size_t)(n - NUM_USERS) * DIM4;
    float r = rinv[n] * G0;
    f32x4 c0 = __builtin_nontemporal_load(&row[4 * j]);
    f32x4 c1 = __builtin_nontemporal_load(&row[4 * j + 1]);
    f32x4 c2 = __builtin_nontemporal_load(&row[4 * j + 2]);
    f32x4 c3 = __builtin_nontemporal_load(&row[4 * j + 3]);
    uint4 o;
    o.x = enc_hi(r * c0.z, r * c0.w, enc_lo(r * c0.x, r * c0.y, 0u));
    o.y = enc_hi(r * c1.z, r * c1.w, enc_lo(r * c1.x, r * c1.y, 0u));
    o.z = enc_hi(r * c2.z, r * c2.w, enc_lo(r * c2.x, r * c2.y, 0u));
    o.w = enc_hi(r * c3.z, r * c3.w, enc_lo(r * c3.x, r * c3.y, 0u));
    e16f8[i] = o;
}

// ---------- SpMM fp8: 16-lane group per row, fp32 accumulate ----------
// Row = 128 B fp8 (16 lanes x 8 B). csr indices loaded coalesced per 16-edge
// window, shfl-broadcast; all 16 gathers issued back-to-back; invalid slots
// clamp to zero row. HW cvt_pk_f32_fp8 decodes; acc scaled by 4*rinv^2
// (gain-ratio fold) and re-encoded fp8.

template <int MASKED>
__global__ __launch_bounds__(256) void spmm_f8_kernel(
        const uint2* __restrict__ tab,       // (N_NODES+1) rows x 16 uint2
        const int* __restrict__ row_start,
        const int* __restrict__ csr_src,
        const float* __restrict__ rinv,
        const int* __restrict__ mark,
        uint2* __restrict__ out) {
    int t = threadIdx.x;
    int n = blockIdx.x * 16 + (t >> 4);
    if (n >= N_NODES) return;
    if (MASKED && !mark[n]) return;
    int lane = t & 15;
    int gbase = t & 48;  // group base lane within wave64
    int beg = row_start[n], end = row_start[n + 1];
    const uint2* tabl = tab + lane;
    f32x2 a0 = {0.f, 0.f}, a1 = {0.f, 0.f}, a2 = {0.f, 0.f}, a3 = {0.f, 0.f};

    for (int base = beg; base < end; base += 16) {
        int eidx = base + lane;
        int myedge = (eidx < end) ? csr_src[eidx] : N_NODES;  // clamp -> zero row
        int s[16];
#pragma unroll
        for (int k = 0; k < 16; ++k) s[k] = __shfl(myedge, gbase + k, 64);
        uint2 h[16];
#pragma unroll
        for (int k = 0; k < 16; ++k) h[k] = tabl[s[k] << 4];
#pragma unroll
        for (int k = 0; k < 16; ++k) {
            a0 += f8x2_lo(h[k].x);
            a1 += f8x2_hi(h[k].x);
            a2 += f8x2_lo(h[k].y);
            a3 += f8x2_hi(h[k].y);
        }
    }

    float f = rinv[n];
    f = 4.0f * f * f;   // rinv^2 * (G_next/G_cur)
    a0 *= f; a1 *= f; a2 *= f; a3 *= f;
    uint2 o;
    o.x = enc_hi(a1[0], a1[1], enc_lo(a0[0], a0[1], 0u));
    o.y = enc_hi(a3[0], a3[1], enc_lo(a2[0], a2[1], 0u));
    out[((size_t)n << 4) + lane] = o;  // 16 lanes x 8 B = 128 B coalesced
}

// ---------- fused epilogue: acc = emb0 + sdeg*(w1/G1+w2/G2) + rinv/G2*sum_N w2; dot ----------
// 128 threads = 4 batch elems x (2 nodes x 16 lanes). Lane owns 8 channels.

__global__ void epilogue_kernel(const f32x4* __restrict__ ue4,
                                const f32x4* __restrict__ ie4,
                                const uint2* __restrict__ w1f8,
                                const uint2* __restrict__ w2f8,
                                const int* __restrict__ row_start,
                                const int* __restrict__ csr_src,
                                const float* __restrict__ rinv,
                                const float* __restrict__ sdeg,
                                const int* __restrict__ users,
                                const int* __restrict__ items,
                                float* __restrict__ out) {
    int t = threadIdx.x;
    int elem = blockIdx.x * 4 + (t >> 5);
    int half = (t >> 4) & 1;
    int lane = t & 15;
    int node = half ? (NUM_USERS + items[elem]) : users[elem];

    const f32x4* erow = (node < NUM_USERS) ? ue4 + (size_t)node * DIM4
                                           : ie4 + (size_t)(node - NUM_USERS) * DIM4;
    f32x4 f0 = erow[2 * lane];
    f32x4 f1 = erow[2 * lane + 1];
    float a[8] = {f0.x, f0.y, f0.z, f0.w, f1.x, f1.y, f1.z, f1.w};

    float sd = sdeg[node];
    uint2 d1 = w1f8[(size_t)node * 16 + lane];
    uint2 d2 = w2f8[(size_t)node * 16 + lane];
    f32x2 p0 = f8x2_lo(d1.x), p1 = f8x2_hi(d1.x), p2 = f8x2_lo(d1.y), p3 = f8x2_hi(d1.y);
    f32x2 q0 = f8x2_lo(d2.x), q1 = f8x2_hi(d2.x), q2 = f8x2_lo(d2.y), q3 = f8x2_hi(d2.y);
    a[0] += sd * (p0[0] * INV_G1 + q0[0] * INV_G2);
    a[1] += sd * (p0[1] * INV_G1 + q0[1] * INV_G2);
    a[2] += sd * (p1[0] * INV_G1 + q1[0] * INV_G2);
    a[3] += sd * (p1[1] * INV_G1 + q1[1] * INV_G2);
    a[4] += sd * (p2[0] * INV_G1 + q2[0] * INV_G2);
    a[5] += sd * (p2[1] * INV_G1 + q2[1] * INV_G2);
    a[6] += sd * (p3[0] * INV_G1 + q3[0] * INV_G2);
    a[7] += sd * (p3[1] * INV_G1 + q3[1] * INV_G2);

    int beg = row_start[node], end = row_start[node + 1];
    f32x2 b0 = {0.f, 0.f}, b1 = {0.f, 0.f}, b2 = {0.f, 0.f}, b3 = {0.f, 0.f};
    for (int e = beg; e < end; ++e) {
        int s0 = csr_src[e];
        uint2 g = w2f8[(size_t)s0 * 16 + lane];
        b0 += f8x2_lo(g.x);
        b1 += f8x2_hi(g.x);
        b2 += f8x2_lo(g.y);
        b3 += f8x2_hi(g.y);
    }
    float rv = rinv[node] * INV_G2;
    a[0] += rv * b0[0]; a[1] += rv * b0[1];
    a[2] += rv * b1[0]; a[3] += rv * b1[1];
    a[4] += rv * b2[0]; a[5] += rv * b2[1];
    a[6] += rv * b3[0]; a[7] += rv * b3[1];

    int wl = t & 63;
    float p = 0.f;
#pragma unroll
    for (int j = 0; j < 8; ++j) p += a[j] * __shfl(a[j], wl ^ 16, 64);
    for (int off = 8; off > 0; off >>= 1) p += __shfl_down(p, off, 16);
    if (half == 0 && lane == 0) out[elem] = p * (1.0f / 16.0f);
}

extern "C" void kernel_launch(void* const* d_in, const int* in_sizes, int n_in,
                              void* d_out, int out_size, void* d_ws, size_t ws_size,
                              hipStream_t stream) {
    const f32x4* ue4 = (const f32x4*)d_in[0];
    const f32x4* ie4 = (const f32x4*)d_in[1];
    const int*   src   = (const int*)d_in[2];
    const int*   dst   = (const int*)d_in[3];
    const int*   users = (const int*)d_in[5];
    const int*   items = (const int*)d_in[6];
    float* out = (float*)d_out;

    const size_t frow = (size_t)(N_NODES + 1) * 16;   // uint2 per fp8 table
    char* ws = (char*)d_ws;
    uint2* e16f8 = (uint2*)ws;  ws += frow * sizeof(uint2);
    uint2* w1f8  = (uint2*)ws;  ws += frow * sizeof(uint2);
    uint2* w2f8  = (uint2*)ws;  ws += frow * sizeof(uint2);
    int*   row_start = (int*)ws;    ws += (size_t)(N_NODES + 1) * sizeof(int);
    float* rinv      = (float*)ws;  ws += (size_t)N_NODES * sizeof(float);
    float* sdeg      = (float*)ws;  ws += (size_t)N_NODES * sizeof(float);
    int*   mark      = (int*)ws;    ws += (size_t)N_NODES * sizeof(int);
    int*   bcur      = (int*)ws;    ws += (size_t)NBUCK * sizeof(int);   // adjacent to mark
    ws = (char*)(((size_t)ws + 255) & ~(size_t)255);
    int*   tmp       = (int*)ws;    ws += (size_t)NBUCK * CAPB * sizeof(int);
    int*   csr_src   = (int*)ws;    ws += (size_t)N_EDGES * sizeof(int);

    // one memset covers mark + bcur (contiguous)
    hipMemsetAsync(mark, 0, (size_t)N_NODES * sizeof(int) + (size_t)NBUCK * sizeof(int), stream);

    // --- binned CSR build ---
    bucket_scatter_kernel<<<NCHUNK, 512, 0, stream>>>(src, dst, bcur, tmp);
    place_kernel<<<NBUCK, 512, 0, stream>>>(bcur, tmp, row_start, rinv, sdeg, csr_src);

    // --- fused mark + fp8 pre-scaled table (+ zero row init) ---
    mark_conv_kernel<<<MARK_BLOCKS + CONV_BLOCKS, 256, 0, stream>>>(
        ue4, ie4, rinv, (uint4*)e16f8, (uint4*)w1f8, users, items, row_start, csr_src, mark);

    // --- layer 1 (all rows) ---
    spmm_f8_kernel<0><<<(N_NODES + 15) / 16, 256, 0, stream>>>(
        e16f8, row_start, csr_src, rinv, nullptr, w1f8);

    // --- layer 2 (marked rows only) ---
    spmm_f8_kernel<1><<<(N_NODES + 15) / 16, 256, 0, stream>>>(
        w1f8, row_start, csr_src, rinv, mark, w2f8);

    // --- fused epilogue: layers 0-3 at batch rows + dot ---
    epilogue_kernel<<<BATCH / 4, 128, 0, stream>>>(
        ue4, ie4, w1f8, w2f8, row_start, csr_src, rinv, sdeg, users, items, out);
}